// Round 4
// baseline (916.283 us; speedup 1.0000x reference)
//
#include <hip/hip_runtime.h>

#define B_SIZE 1024
#define T_LEN  256
#define D_IN   64
#define HC     32

__device__ __forceinline__ float frcp(float x){ return __builtin_amdgcn_rcpf(x); }
__device__ __forceinline__ float rfl(float x){
    return __uint_as_float(__builtin_amdgcn_readfirstlane(__float_as_uint(x)));
}
__device__ __forceinline__ float rdlane(float x, int l){
    return __int_as_float(__builtin_amdgcn_readlane(__float_as_int(x), l));
}
// tanh(x) = 1 - 2/(e^{2x}+1)
__device__ __forceinline__ float ftanh(float x){
    return 1.f - 2.f*frcp(__expf(2.f*x) + 1.f);
}
__device__ __forceinline__ float fsigmoid(float x){
    return frcp(1.f + __expf(-x));
}

template<int CTRL>
__device__ __forceinline__ int dppmov(int x){
    return __builtin_amdgcn_update_dpp(x, x, CTRL, 0xF, 0xF, false);
}

// value of lane (lane ^ M) — R3-proven primitives only:
//  M with bit32: ds_bpermute full-wave xor (via __shfl)
//  M in {1,2,3}: quad_perm DPP ; M==8: row_ror:8 DPP
//  other M<=31 : ds_swizzle BitMode (xor<<10)|0x1F
template<int M>
__device__ __forceinline__ float xshuf(float xf, unsigned lane){
    if constexpr (M == 0){
        return xf;
    } else if constexpr (M & 32){
        return __shfl(xf, (int)(lane ^ (unsigned)M), 64);
    } else if constexpr ((M & ~3) == 0){
        constexpr int ctrl = (M == 1) ? 0xB1 : (M == 2) ? 0x4E : 0x1B;
        return __int_as_float(dppmov<ctrl>(__float_as_int(xf)));
    } else if constexpr (M == 8){
        return __int_as_float(dppmov<0x128>(__float_as_int(xf)));
    } else {
        return __int_as_float(__builtin_amdgcn_ds_swizzle(__float_as_int(xf), (M << 10) | 0x1F));
    }
}

// ---- compile-time GF(2) tracking of the CNOT-ring basis relabeling (R3-verified) ----
struct QMasks { int M[3][6]; int S[3][6]; int R[6]; };
constexpr QMasks qmasks(){
    QMasks qm{};
    unsigned m[6], n[6];
    for (int i = 0; i < 6; i++){ m[i] = 1u << i; n[i] = 1u << i; }
    for (int l = 0; l < 3; l++){
        for (int q = 0; q < 6; q++){
            unsigned u = m[q], r = 0;
            for (int i = 0; i < 6; i++) if ((u >> i) & 1u) r |= (32u >> i);
            qm.S[l][q] = (int)r;
            unsigned u2 = 0;
            for (int i = 0; i < 6; i++) u2 |= ((n[i] >> q) & 1u) << i;
            unsigned r2 = 0;
            for (int i = 0; i < 6; i++) if ((u2 >> i) & 1u) r2 |= (32u >> i);
            qm.M[l][q] = (int)r2;
        }
        for (int q = 0; q < 6; q++) m[(q + 1) % 6] ^= m[q];
        n[0] ^= n[5];
        for (int q = 4; q >= 0; q--) n[q + 1] ^= n[q];
    }
    for (int i = 0; i < 6; i++){
        unsigned u = m[i], r = 0;
        for (int j = 0; j < 6; j++) if ((u >> j) & 1u) r |= (32u >> j);
        qm.R[i] = (int)r;
    }
    return qm;
}
constexpr QMasks QM = qmasks();

// ---------------- conv0 (R1-proven): x (B,T,64) -> t0 (B,32,T) ----------------
__global__ __launch_bounds__(256) void conv0_kernel(const float* __restrict__ x,
    const float* __restrict__ w0, const float* __restrict__ b0, float* __restrict__ out)
{
    __shared__ float xs[130*65];
    __shared__ float wl[192*32];
    const int tid = threadIdx.x;
    const int b  = blockIdx.x >> 1;
    const int s0 = (blockIdx.x & 1) * 128;

    for (int idx = tid; idx < 130*64; idx += 256){
        int r = idx >> 6, d = idx & 63;
        int s = s0 - 1 + r;
        float v = 0.f;
        if (s >= 0 && s < T_LEN) v = x[(size_t)b*(T_LEN*D_IN) + (size_t)s*D_IN + d];
        xs[r*65 + d] = v;
    }
    for (int idx = tid; idx < 192*32; idx += 256){
        int r = idx >> 5, c = idx & 31;
        wl[idx] = w0[c*192 + r];
    }
    __syncthreads();

    const int c0 = (tid & 7) * 4;
    const int sl = (tid >> 3) * 4;
    float acc[4][4];
    #pragma unroll
    for (int ci = 0; ci < 4; ci++){
        float bb = b0[c0+ci];
        #pragma unroll
        for (int m = 0; m < 4; m++) acc[ci][m] = bb;
    }
    for (int d = 0; d < 64; d++){
        float xv[6];
        #pragma unroll
        for (int o = 0; o < 6; o++) xv[o] = xs[(sl+o)*65 + d];
        #pragma unroll
        for (int kk = 0; kk < 3; kk++){
            const float4 wv = *(const float4*)&wl[(d*3+kk)*32 + c0];
            float w4[4] = {wv.x, wv.y, wv.z, wv.w};
            #pragma unroll
            for (int ci = 0; ci < 4; ci++)
                #pragma unroll
                for (int m = 0; m < 4; m++)
                    acc[ci][m] += xv[m+kk]*w4[ci];
        }
    }
    #pragma unroll
    for (int ci = 0; ci < 4; ci++){
        float4 v;
        v.x = fmaxf(acc[ci][0], 0.f); v.y = fmaxf(acc[ci][1], 0.f);
        v.z = fmaxf(acc[ci][2], 0.f); v.w = fmaxf(acc[ci][3], 0.f);
        *(float4*)&out[(size_t)b*(HC*T_LEN) + (size_t)(c0+ci)*T_LEN + (s0+sl)] = v;
    }
}

// ------------- mid conv (R1-proven): (B,32,T) -> (B,32,T) or (T,B,32) -------------
template<bool TOUT>
__global__ __launch_bounds__(256) void convm_kernel(const float* __restrict__ in,
    const float* __restrict__ w, const float* __restrict__ bias, float* __restrict__ out)
{
    __shared__ float xs[130*33];
    __shared__ float wl[96*32];
    const int tid = threadIdx.x;
    const int b  = blockIdx.x >> 1;
    const int s0 = (blockIdx.x & 1) * 128;

    for (int idx = tid; idx < 32*130; idx += 256){
        int ci = idx / 130; int r = idx - ci*130;
        int s = s0 - 1 + r;
        float v = 0.f;
        if (s >= 0 && s < T_LEN) v = in[(size_t)b*(HC*T_LEN) + (size_t)ci*T_LEN + s];
        xs[r*33 + ci] = v;
    }
    for (int idx = tid; idx < 96*32; idx += 256){
        int r = idx >> 5, c = idx & 31;
        wl[idx] = w[c*96 + r];
    }
    __syncthreads();

    const int c0 = (tid & 7) * 4;
    const int sl = (tid >> 3) * 4;
    float acc[4][4];
    #pragma unroll
    for (int ci = 0; ci < 4; ci++){
        float bb = bias[c0+ci];
        #pragma unroll
        for (int m = 0; m < 4; m++) acc[ci][m] = bb;
    }
    for (int ci2 = 0; ci2 < 32; ci2++){
        float xv[6];
        #pragma unroll
        for (int o = 0; o < 6; o++) xv[o] = xs[(sl+o)*33 + ci2];
        #pragma unroll
        for (int kk = 0; kk < 3; kk++){
            const float4 wv = *(const float4*)&wl[(ci2*3+kk)*32 + c0];
            float w4[4] = {wv.x, wv.y, wv.z, wv.w};
            #pragma unroll
            for (int ci = 0; ci < 4; ci++)
                #pragma unroll
                for (int m = 0; m < 4; m++)
                    acc[ci][m] += xv[m+kk]*w4[ci];
        }
    }
    if (!TOUT){
        #pragma unroll
        for (int ci = 0; ci < 4; ci++){
            float4 v;
            v.x = fmaxf(acc[ci][0], 0.f); v.y = fmaxf(acc[ci][1], 0.f);
            v.z = fmaxf(acc[ci][2], 0.f); v.w = fmaxf(acc[ci][3], 0.f);
            *(float4*)&out[(size_t)b*(HC*T_LEN) + (size_t)(c0+ci)*T_LEN + (s0+sl)] = v;
        }
    } else {
        #pragma unroll
        for (int m = 0; m < 4; m++){
            int s = s0 + sl + m;
            float4 v;
            v.x = fmaxf(acc[0][m], 0.f); v.y = fmaxf(acc[1][m], 0.f);
            v.z = fmaxf(acc[2][m], 0.f); v.w = fmaxf(acc[3][m], 0.f);
            *(float4*)&out[(size_t)s*(B_SIZE*HC) + (size_t)b*HC + c0] = v;
        }
    }
}

// -------- scan: TWO batch elements per wave (b and b+512), interleaved ILP --------
__global__ __launch_bounds__(256, 1) void scan_kernel(
    const float* __restrict__ tS,
    const float* __restrict__ Wih, const float* __restrict__ Whh,
    const float* __restrict__ bih, const float* __restrict__ bhh,
    const float* __restrict__ qw,  const float* __restrict__ Wfc,
    const float* __restrict__ bfc, const float* __restrict__ Wout,
    const float* __restrict__ bout, float* __restrict__ out)
{
    const unsigned lane = threadIdx.x & 63u;
    const int wv = threadIdx.x >> 6;
    const int w_ = __builtin_amdgcn_readfirstlane(blockIdx.x * 4 + wv);
    const int bA = w_, bB = w_ + 512;
    const int r1 = lane, r2 = lane + 64;       // gate rows: [i f | g o]
    const int k  = lane & 31;

    // shared register-resident gate weight rows (128 VGPRs, element-independent)
    float wA[32], wB[32], uA[32], uB[32];
    #pragma unroll
    for (int j4 = 0; j4 < 8; j4++){
        float4 a  = ((const float4*)Wih)[r1*8 + j4];
        float4 c_ = ((const float4*)Wih)[r2*8 + j4];
        float4 d_ = ((const float4*)Whh)[r1*8 + j4];
        float4 e  = ((const float4*)Whh)[r2*8 + j4];
        wA[j4*4+0]=a.x;  wA[j4*4+1]=a.y;  wA[j4*4+2]=a.z;  wA[j4*4+3]=a.w;
        wB[j4*4+0]=c_.x; wB[j4*4+1]=c_.y; wB[j4*4+2]=c_.z; wB[j4*4+3]=c_.w;
        uA[j4*4+0]=d_.x; uA[j4*4+1]=d_.y; uA[j4*4+2]=d_.z; uA[j4*4+3]=d_.w;
        uB[j4*4+0]=e.x;  uB[j4*4+1]=e.y;  uB[j4*4+2]=e.z;  uB[j4*4+3]=e.w;
    }
    const float bias1 = bih[r1] + bhh[r1];
    const float bias2 = bih[r2] + bhh[r2];

    float wfcr[6];
    #pragma unroll
    for (int j = 0; j < 6; j++) wfcr[j] = Wfc[k*6 + j];
    const float bfcl  = bfc[k];
    const float woutl = (lane < 32) ? Wout[k] : 0.f;
    const float boutv = bout[0];

    float cgv[18], ssin[18];
    #pragma unroll
    for (int g = 0; g < 18; g++){
        int l = g / 6, q = g % 6;
        float a = 0.5f * qw[g];
        float cv = __cosf(a), sv = __sinf(a);
        cgv[g] = rfl(cv);
        unsigned sm = (unsigned)QM.S[l][q];
        ssin[g] = (__builtin_popcount(sm & lane) & 1) ? sv : -sv;
    }
    float wsgn[6];
    #pragma unroll
    for (int j = 0; j < 6; j++) wsgn[j] = (lane & (1u << j)) ? -1.f : 1.f;
    const bool qs[6] = { (lane & 32u) != 0, (lane & 16u) != 0, (lane & 8u) != 0,
                         (lane & 4u) != 0,  (lane & 2u) != 0,  (lane & 1u) != 0 };

    float hA = 0.f, cAc = 0.f, hB = 0.f, cBc = 0.f;
    const float* xbA = tS + (size_t)bA * HC;
    const float* xbB = tS + (size_t)bB * HC;

    float4 xfA[8], xfB[8];
    #pragma unroll
    for (int j4 = 0; j4 < 8; j4++){ xfA[j4] = ((const float4*)xbA)[j4]; xfB[j4] = ((const float4*)xbB)[j4]; }

    #pragma clang loop unroll(disable)
    for (int s = 0; s < T_LEN; s++){
        float xtA[32], xtB[32];
        #pragma unroll
        for (int j4 = 0; j4 < 8; j4++){
            xtA[j4*4+0]=xfA[j4].x; xtA[j4*4+1]=xfA[j4].y; xtA[j4*4+2]=xfA[j4].z; xtA[j4*4+3]=xfA[j4].w;
            xtB[j4*4+0]=xfB[j4].x; xtB[j4*4+1]=xfB[j4].y; xtB[j4*4+2]=xfB[j4].z; xtB[j4*4+3]=xfB[j4].w;
        }
        { // prefetch next step for both streams
            int s2 = (s + 1 < T_LEN) ? s + 1 : s;
            const float4* nA = (const float4*)(xbA + (size_t)s2*(B_SIZE*HC));
            const float4* nB = (const float4*)(xbB + (size_t)s2*(B_SIZE*HC));
            #pragma unroll
            for (int j4 = 0; j4 < 8; j4++){ xfA[j4] = nA[j4]; xfB[j4] = nB[j4]; }
        }

        // ---- LSTM gates (A and B interleaved; 8 independent FMA chains) ----
        float a1aA = bias1, a1bA = 0.f, a2aA = bias2, a2bA = 0.f;
        float a1aB = bias1, a1bB = 0.f, a2aB = bias2, a2bB = 0.f;
        #pragma unroll
        for (int j = 0; j < 32; j += 2){
            a1aA += xtA[j]*wA[j];   a1bA += xtA[j+1]*wA[j+1];
            a2aA += xtA[j]*wB[j];   a2bA += xtA[j+1]*wB[j+1];
            a1aB += xtB[j]*wA[j];   a1bB += xtB[j+1]*wA[j+1];
            a2aB += xtB[j]*wB[j];   a2bB += xtB[j+1]*wB[j+1];
        }
        #pragma unroll
        for (int j = 0; j < 32; j += 2){
            float h0A = rdlane(hA, j), h1A = rdlane(hA, j+1);
            float h0B = rdlane(hB, j), h1B = rdlane(hB, j+1);
            a1aA += h0A*uA[j];  a1bA += h1A*uA[j+1];
            a2aA += h0A*uB[j];  a2bA += h1A*uB[j+1];
            a1aB += h0B*uA[j];  a1bB += h1B*uA[j+1];
            a2aB += h0B*uB[j];  a2bB += h1B*uB[j+1];
        }
        float acc1A = a1aA + a1bA, acc2A = a2aA + a2bA;
        float acc1B = a1aB + a1bB, acc2B = a2aB + a2bB;

        float sigA_A = fsigmoid(acc1A);
        float sigA_B = fsigmoid(acc1B);
        float argB_A = (lane < 32) ? acc2A : 0.5f*acc2A;
        float argB_B = (lane < 32) ? acc2B : 0.5f*acc2B;
        float ttA = ftanh(argB_A), ttB = ftanh(argB_B);
        float actB_A = (lane < 32) ? ttA : (0.5f + 0.5f*ttA);
        float actB_B = (lane < 32) ? ttB : (0.5f + 0.5f*ttB);
        float fsigA = xshuf<32>(sigA_A, lane);
        float fsigB = xshuf<32>(sigA_B, lane);
        float osigA = xshuf<32>(actB_A, lane);
        float osigB = xshuf<32>(actB_B, lane);
        cAc = fsigA*cAc + sigA_A*actB_A;
        cBc = fsigB*cBc + sigA_B*actB_B;
        float hnA = osigA * ftanh(cAc);
        float hnB = osigB * ftanh(cBc);

        // ---- logistic + henon ----
        hnA = 3.99f * hnA * (1.f - hnA);
        hnB = 3.99f * hnB * (1.f - hnB);
        float x0A = rdlane(hnA, 0), y0A = rdlane(hnA, 1);
        float x0B = rdlane(hnB, 0), y0B = rdlane(hnB, 1);
        float xnvA = 1.f - 1.4f*x0A*x0A + y0A, ynvA = 0.3f * x0A;
        float xnvB = 1.f - 1.4f*x0B*x0B + y0B, ynvB = 0.3f * x0B;

        // ---- product-state init ----
        float angA[6], angB[6];
        angA[0] = 0.5f*xnvA; angA[1] = 0.5f*ynvA;
        angB[0] = 0.5f*xnvB; angB[1] = 0.5f*ynvB;
        angA[2] = 0.5f*rdlane(hnA, 2); angA[3] = 0.5f*rdlane(hnA, 3);
        angA[4] = 0.5f*rdlane(hnA, 4); angA[5] = 0.5f*rdlane(hnA, 5);
        angB[2] = 0.5f*rdlane(hnB, 2); angB[3] = 0.5f*rdlane(hnB, 3);
        angB[4] = 0.5f*rdlane(hnB, 4); angB[5] = 0.5f*rdlane(hnB, 5);
        float caA[6], saA[6], caB[6], saB[6];
        #pragma unroll
        for (int j = 0; j < 6; j++){
            caA[j] = __cosf(angA[j]); saA[j] = __sinf(angA[j]);
            caB[j] = __cosf(angB[j]); saB[j] = __sinf(angB[j]);
        }

        float frA[6], fiA[6], frB[6], fiB[6];
        #pragma unroll
        for (int i = 0; i < 6; i++){
            const int i1 = (i+1)%6, i2 = (i+2)%6;
            {
                float cx=caA[i], sx=saA[i], cy=caA[i1], sy=saA[i1], cz=caA[i2], sz=saA[i2];
                float w0r = cy*cx, w0i = sy*sx, w1r = sy*cx, w1i = -cy*sx;
                float q0r = cz*w0r + sz*w0i, q0i = cz*w0i - sz*w0r;
                float q1r = cz*w1r - sz*w1i, q1i = cz*w1i + sz*w1r;
                frA[i] = qs[i] ? q1r : q0r;  fiA[i] = qs[i] ? q1i : q0i;
            }
            {
                float cx=caB[i], sx=saB[i], cy=caB[i1], sy=saB[i1], cz=caB[i2], sz=saB[i2];
                float w0r = cy*cx, w0i = sy*sx, w1r = sy*cx, w1i = -cy*sx;
                float q0r = cz*w0r + sz*w0i, q0i = cz*w0i - sz*w0r;
                float q1r = cz*w1r - sz*w1i, q1i = cz*w1i + sz*w1r;
                frB[i] = qs[i] ? q1r : q0r;  fiB[i] = qs[i] ? q1i : q0i;
            }
        }
        float arA, aiA, arB, aiB;
        {
            float t01r = frA[0]*frA[1] - fiA[0]*fiA[1], t01i = frA[0]*fiA[1] + fiA[0]*frA[1];
            float t23r = frA[2]*frA[3] - fiA[2]*fiA[3], t23i = frA[2]*fiA[3] + fiA[2]*frA[3];
            float t45r = frA[4]*frA[5] - fiA[4]*fiA[5], t45i = frA[4]*fiA[5] + fiA[4]*frA[5];
            float t03r = t01r*t23r - t01i*t23i,         t03i = t01r*t23i + t01i*t23r;
            arA = t03r*t45r - t03i*t45i;                aiA = t03r*t45i + t03i*t45r;
        }
        {
            float t01r = frB[0]*frB[1] - fiB[0]*fiB[1], t01i = frB[0]*fiB[1] + fiB[0]*frB[1];
            float t23r = frB[2]*frB[3] - fiB[2]*fiB[3], t23i = frB[2]*fiB[3] + fiB[2]*frB[3];
            float t45r = frB[4]*frB[5] - fiB[4]*fiB[5], t45i = frB[4]*fiB[5] + fiB[4]*frB[5];
            float t03r = t01r*t23r - t01i*t23i,         t03i = t01r*t23i + t01i*t23r;
            arB = t03r*t45r - t03i*t45i;                aiB = t03r*t45i + t03i*t45r;
        }

        // ---- entangling layers: both streams through each gate back-to-back ----
        #define GATE(L,Q) { \
            constexpr int MM = QM.M[L][Q]; \
            float cg = cgv[(L)*6+(Q)], ss = ssin[(L)*6+(Q)]; \
            float brA = xshuf<MM>(arA, lane), biA = xshuf<MM>(aiA, lane); \
            float brB = xshuf<MM>(arB, lane), biB = xshuf<MM>(aiB, lane); \
            arA = cg*arA + ss*brA; aiA = cg*aiA + ss*biA; \
            arB = cg*arB + ss*brB; aiB = cg*aiB + ss*biB; }
        GATE(0,0) GATE(0,1) GATE(0,2) GATE(0,3) GATE(0,4) GATE(0,5)
        GATE(1,0) GATE(1,1) GATE(1,2) GATE(1,3) GATE(1,4) GATE(1,5)
        GATE(2,0) GATE(2,1) GATE(2,2) GATE(2,3) GATE(2,4) GATE(2,5)
        #undef GATE

        // ---- expvals: WHT butterfly on both probability vectors ----
        float wpA = arA*arA + aiA*aiA;
        float wpB = arB*arB + aiB*aiB;
        wpA = wsgn[0]*wpA + xshuf< 1>(wpA, lane);  wpB = wsgn[0]*wpB + xshuf< 1>(wpB, lane);
        wpA = wsgn[1]*wpA + xshuf< 2>(wpA, lane);  wpB = wsgn[1]*wpB + xshuf< 2>(wpB, lane);
        wpA = wsgn[2]*wpA + xshuf< 4>(wpA, lane);  wpB = wsgn[2]*wpB + xshuf< 4>(wpB, lane);
        wpA = wsgn[3]*wpA + xshuf< 8>(wpA, lane);  wpB = wsgn[3]*wpB + xshuf< 8>(wpB, lane);
        wpA = wsgn[4]*wpA + xshuf<16>(wpA, lane);  wpB = wsgn[4]*wpB + xshuf<16>(wpB, lane);
        wpA = wsgn[5]*wpA + xshuf<32>(wpA, lane);  wpB = wsgn[5]*wpB + xshuf<32>(wpB, lane);

        float updA = bfcl + (wfcr[0]*rdlane(wpA, QM.R[0]) + wfcr[1]*rdlane(wpA, QM.R[1]))
                          + (wfcr[2]*rdlane(wpA, QM.R[2]) + wfcr[3]*rdlane(wpA, QM.R[3]))
                          + (wfcr[4]*rdlane(wpA, QM.R[4]) + wfcr[5]*rdlane(wpA, QM.R[5]));
        float updB = bfcl + (wfcr[0]*rdlane(wpB, QM.R[0]) + wfcr[1]*rdlane(wpB, QM.R[1]))
                          + (wfcr[2]*rdlane(wpB, QM.R[2]) + wfcr[3]*rdlane(wpB, QM.R[3]))
                          + (wfcr[4]*rdlane(wpB, QM.R[4]) + wfcr[5]*rdlane(wpB, QM.R[5]));

        float hselA = hnA, hselB = hnB;
        hselA = (lane == 0u) ? xnvA : hselA;  hselA = (lane == 1u) ? ynvA : hselA;
        hselB = (lane == 0u) ? xnvB : hselB;  hselB = (lane == 1u) ? ynvB : hselB;
        hA = hselA + updA;
        hB = hselB + updB;
    }

    // ---- outputs ----
    float pvA = (lane < 32) ? hA*woutl : 0.f;
    float pvB = (lane < 32) ? hB*woutl : 0.f;
    #pragma unroll
    for (int off = 32; off; off >>= 1){
        pvA += __shfl_xor(pvA, off, 64);
        pvB += __shfl_xor(pvB, off, 64);
    }
    if (lane == 0){
        out[bA] = fsigmoid(pvA + boutv);
        out[bB] = fsigmoid(pvB + boutv);
    }
}

extern "C" void kernel_launch(void* const* d_in, const int* in_sizes, int n_in,
                              void* d_out, int out_size, void* d_ws, size_t ws_size,
                              hipStream_t stream)
{
    (void)in_sizes; (void)n_in; (void)out_size; (void)ws_size;
    const float* x    = (const float*)d_in[0];
    const float* w0   = (const float*)d_in[1];
    const float* b0   = (const float*)d_in[2];
    const float* w1   = (const float*)d_in[3];
    const float* b1   = (const float*)d_in[4];
    const float* w2   = (const float*)d_in[5];
    const float* b2   = (const float*)d_in[6];
    const float* Wih  = (const float*)d_in[7];
    const float* Whh  = (const float*)d_in[8];
    const float* bih  = (const float*)d_in[9];
    const float* bhh  = (const float*)d_in[10];
    const float* qw   = (const float*)d_in[11];
    const float* Wfc  = (const float*)d_in[12];
    const float* bfc  = (const float*)d_in[13];
    const float* Wout = (const float*)d_in[14];
    const float* bout = (const float*)d_in[15];
    float* out = (float*)d_out;

    float* t0 = (float*)d_ws;                              // (B,32,T) 32 MB
    float* t1 = t0 + (size_t)B_SIZE*HC*T_LEN;              // (B,32,T) 32 MB
    float* tS = t0;                                        // (T,B,32) reuses t0

    conv0_kernel<<<2048, 256, 0, stream>>>(x, w0, b0, t0);
    convm_kernel<false><<<2048, 256, 0, stream>>>(t0, w1, b1, t1);
    convm_kernel<true ><<<2048, 256, 0, stream>>>(t1, w2, b2, tS);
    scan_kernel<<<128, 256, 0, stream>>>(tS, Wih, Whh, bih, bhh, qw, Wfc, bfc, Wout, bout, out);
}

// Round 5
// 681.010 us; speedup vs baseline: 1.3455x; 1.3455x over previous
//
#include <hip/hip_runtime.h>

#define B_SIZE 1024
#define T_LEN  256
#define D_IN   64
#define HC     32

typedef int v2i_t __attribute__((ext_vector_type(2)));

__device__ __forceinline__ float frcp(float x){ return __builtin_amdgcn_rcpf(x); }
__device__ __forceinline__ float rfl(float x){
    return __uint_as_float(__builtin_amdgcn_readfirstlane(__float_as_uint(x)));
}
__device__ __forceinline__ float rdlane(float x, int l){
    return __int_as_float(__builtin_amdgcn_readlane(__float_as_int(x), l));
}
// tanh(x) = 1 - 2/(e^{2x}+1)
__device__ __forceinline__ float ftanh(float x){
    return 1.f - 2.f*frcp(__expf(2.f*x) + 1.f);
}
__device__ __forceinline__ float fsigmoid(float x){
    return frcp(1.f + __expf(-x));
}

template<int CTRL>
__device__ __forceinline__ int dppmov(int x){
    return __builtin_amdgcn_update_dpp(x, x, CTRL, 0xF, 0xF, false);
}

// xor-exchange within 16-lane rows, masks 1..15, pure DPP (1-2 ops):
// generators: ^1=quad B1, ^2=quad 4E, ^3=quad 1B, ^7=row_half_mirror(0x141),
// ^8=row_ror:8(0x128), ^15=row_mirror(0x140).  ^4=^3*^7, ^12=^3*^15, etc.
template<int M>
__device__ __forceinline__ int dpp_xor(int x){
    static_assert(M >= 1 && M <= 15, "dpp_xor mask");
    constexpr int hi = M & 12;
    constexpr int q  = (hi == 4 || hi == 12) ? ((M & 3) ^ 3) : (M & 3);
    if constexpr (q == 1) x = dppmov<0xB1>(x);
    else if constexpr (q == 2) x = dppmov<0x4E>(x);
    else if constexpr (q == 3) x = dppmov<0x1B>(x);
    if constexpr (hi == 4)       x = dppmov<0x141>(x);
    else if constexpr (hi == 8)  x = dppmov<0x128>(x);
    else if constexpr (hi == 12) x = dppmov<0x140>(x);
    return x;
}

// value of lane (lane ^ M):
//  bits 0-3  -> DPP (mirror decomposition), no DS
//  bit 4 set -> one ds_swizzle covering all of M&31 (R3-proven composite)
//  bit 5     -> permlane32_swap xor-trick (THE experiment this round;
//               r.x^r.y^x is immune to arg-order/row-pairing variants)
template<int M>
__device__ __forceinline__ float xshuf(float xf, unsigned lane){
    (void)lane;
    if constexpr (M == 0) return xf;
    int x = __float_as_int(xf);
    if constexpr (M & 16){
        x = __builtin_amdgcn_ds_swizzle(x, ((M & 31) << 10) | 0x1F);
    } else if constexpr (M & 15){
        x = dpp_xor<M & 15>(x);
    }
    if constexpr (M & 32){
        v2i_t r = __builtin_amdgcn_permlane32_swap(x, x, false, false);
        x = r.x ^ r.y ^ x;
    }
    return __int_as_float(x);
}

// ---- compile-time GF(2) tracking of the CNOT-ring basis relabeling (R3-verified) ----
struct QMasks { int M[3][6]; int S[3][6]; int R[6]; };
constexpr QMasks qmasks(){
    QMasks qm{};
    unsigned m[6], n[6];
    for (int i = 0; i < 6; i++){ m[i] = 1u << i; n[i] = 1u << i; }
    for (int l = 0; l < 3; l++){
        for (int q = 0; q < 6; q++){
            unsigned u = m[q], r = 0;
            for (int i = 0; i < 6; i++) if ((u >> i) & 1u) r |= (32u >> i);
            qm.S[l][q] = (int)r;
            unsigned u2 = 0;
            for (int i = 0; i < 6; i++) u2 |= ((n[i] >> q) & 1u) << i;
            unsigned r2 = 0;
            for (int i = 0; i < 6; i++) if ((u2 >> i) & 1u) r2 |= (32u >> i);
            qm.M[l][q] = (int)r2;
        }
        for (int q = 0; q < 6; q++) m[(q + 1) % 6] ^= m[q];
        n[0] ^= n[5];
        for (int q = 4; q >= 0; q--) n[q + 1] ^= n[q];
    }
    for (int i = 0; i < 6; i++){
        unsigned u = m[i], r = 0;
        for (int j = 0; j < 6; j++) if ((u >> j) & 1u) r |= (32u >> j);
        qm.R[i] = (int)r;
    }
    return qm;
}
constexpr QMasks QM = qmasks();

// ---------------- conv0 (R1-proven): x (B,T,64) -> t0 (B,32,T) ----------------
__global__ __launch_bounds__(256) void conv0_kernel(const float* __restrict__ x,
    const float* __restrict__ w0, const float* __restrict__ b0, float* __restrict__ out)
{
    __shared__ float xs[130*65];
    __shared__ float wl[192*32];
    const int tid = threadIdx.x;
    const int b  = blockIdx.x >> 1;
    const int s0 = (blockIdx.x & 1) * 128;

    for (int idx = tid; idx < 130*64; idx += 256){
        int r = idx >> 6, d = idx & 63;
        int s = s0 - 1 + r;
        float v = 0.f;
        if (s >= 0 && s < T_LEN) v = x[(size_t)b*(T_LEN*D_IN) + (size_t)s*D_IN + d];
        xs[r*65 + d] = v;
    }
    for (int idx = tid; idx < 192*32; idx += 256){
        int r = idx >> 5, c = idx & 31;
        wl[idx] = w0[c*192 + r];
    }
    __syncthreads();

    const int c0 = (tid & 7) * 4;
    const int sl = (tid >> 3) * 4;
    float acc[4][4];
    #pragma unroll
    for (int ci = 0; ci < 4; ci++){
        float bb = b0[c0+ci];
        #pragma unroll
        for (int m = 0; m < 4; m++) acc[ci][m] = bb;
    }
    for (int d = 0; d < 64; d++){
        float xv[6];
        #pragma unroll
        for (int o = 0; o < 6; o++) xv[o] = xs[(sl+o)*65 + d];
        #pragma unroll
        for (int kk = 0; kk < 3; kk++){
            const float4 wv = *(const float4*)&wl[(d*3+kk)*32 + c0];
            float w4[4] = {wv.x, wv.y, wv.z, wv.w};
            #pragma unroll
            for (int ci = 0; ci < 4; ci++)
                #pragma unroll
                for (int m = 0; m < 4; m++)
                    acc[ci][m] += xv[m+kk]*w4[ci];
        }
    }
    #pragma unroll
    for (int ci = 0; ci < 4; ci++){
        float4 v;
        v.x = fmaxf(acc[ci][0], 0.f); v.y = fmaxf(acc[ci][1], 0.f);
        v.z = fmaxf(acc[ci][2], 0.f); v.w = fmaxf(acc[ci][3], 0.f);
        *(float4*)&out[(size_t)b*(HC*T_LEN) + (size_t)(c0+ci)*T_LEN + (s0+sl)] = v;
    }
}

// ------------- mid conv (R1-proven): (B,32,T) -> (B,32,T) or (T,B,32) -------------
template<bool TOUT>
__global__ __launch_bounds__(256) void convm_kernel(const float* __restrict__ in,
    const float* __restrict__ w, const float* __restrict__ bias, float* __restrict__ out)
{
    __shared__ float xs[130*33];
    __shared__ float wl[96*32];
    const int tid = threadIdx.x;
    const int b  = blockIdx.x >> 1;
    const int s0 = (blockIdx.x & 1) * 128;

    for (int idx = tid; idx < 32*130; idx += 256){
        int ci = idx / 130; int r = idx - ci*130;
        int s = s0 - 1 + r;
        float v = 0.f;
        if (s >= 0 && s < T_LEN) v = in[(size_t)b*(HC*T_LEN) + (size_t)ci*T_LEN + s];
        xs[r*33 + ci] = v;
    }
    for (int idx = tid; idx < 96*32; idx += 256){
        int r = idx >> 5, c = idx & 31;
        wl[idx] = w[c*96 + r];
    }
    __syncthreads();

    const int c0 = (tid & 7) * 4;
    const int sl = (tid >> 3) * 4;
    float acc[4][4];
    #pragma unroll
    for (int ci = 0; ci < 4; ci++){
        float bb = bias[c0+ci];
        #pragma unroll
        for (int m = 0; m < 4; m++) acc[ci][m] = bb;
    }
    for (int ci2 = 0; ci2 < 32; ci2++){
        float xv[6];
        #pragma unroll
        for (int o = 0; o < 6; o++) xv[o] = xs[(sl+o)*33 + ci2];
        #pragma unroll
        for (int kk = 0; kk < 3; kk++){
            const float4 wv = *(const float4*)&wl[(ci2*3+kk)*32 + c0];
            float w4[4] = {wv.x, wv.y, wv.z, wv.w};
            #pragma unroll
            for (int ci = 0; ci < 4; ci++)
                #pragma unroll
                for (int m = 0; m < 4; m++)
                    acc[ci][m] += xv[m+kk]*w4[ci];
        }
    }
    if (!TOUT){
        #pragma unroll
        for (int ci = 0; ci < 4; ci++){
            float4 v;
            v.x = fmaxf(acc[ci][0], 0.f); v.y = fmaxf(acc[ci][1], 0.f);
            v.z = fmaxf(acc[ci][2], 0.f); v.w = fmaxf(acc[ci][3], 0.f);
            *(float4*)&out[(size_t)b*(HC*T_LEN) + (size_t)(c0+ci)*T_LEN + (s0+sl)] = v;
        }
    } else {
        #pragma unroll
        for (int m = 0; m < 4; m++){
            int s = s0 + sl + m;
            float4 v;
            v.x = fmaxf(acc[0][m], 0.f); v.y = fmaxf(acc[1][m], 0.f);
            v.z = fmaxf(acc[2][m], 0.f); v.w = fmaxf(acc[3][m], 0.f);
            *(float4*)&out[(size_t)s*(B_SIZE*HC) + (size_t)b*HC + c0] = v;
        }
    }
}

// ---------------- scan: one wave per batch element (R3 core) ----------------
__global__ __launch_bounds__(256, 1) void scan_kernel(
    const float* __restrict__ tS,
    const float* __restrict__ Wih, const float* __restrict__ Whh,
    const float* __restrict__ bih, const float* __restrict__ bhh,
    const float* __restrict__ qw,  const float* __restrict__ Wfc,
    const float* __restrict__ bfc, const float* __restrict__ Wout,
    const float* __restrict__ bout, float* __restrict__ out)
{
    const unsigned lane = threadIdx.x & 63u;
    const int wv   = threadIdx.x >> 6;
    const int b    = __builtin_amdgcn_readfirstlane(blockIdx.x * 4 + wv);
    const int r1 = lane, r2 = lane + 64;       // gate rows: [i f | g o]
    const int k  = lane & 31;

    // register-resident gate weight rows (128 VGPRs)
    float wA[32], wB[32], uA[32], uB[32];
    #pragma unroll
    for (int j4 = 0; j4 < 8; j4++){
        float4 a  = ((const float4*)Wih)[r1*8 + j4];
        float4 c_ = ((const float4*)Wih)[r2*8 + j4];
        float4 d_ = ((const float4*)Whh)[r1*8 + j4];
        float4 e  = ((const float4*)Whh)[r2*8 + j4];
        wA[j4*4+0]=a.x;  wA[j4*4+1]=a.y;  wA[j4*4+2]=a.z;  wA[j4*4+3]=a.w;
        wB[j4*4+0]=c_.x; wB[j4*4+1]=c_.y; wB[j4*4+2]=c_.z; wB[j4*4+3]=c_.w;
        uA[j4*4+0]=d_.x; uA[j4*4+1]=d_.y; uA[j4*4+2]=d_.z; uA[j4*4+3]=d_.w;
        uB[j4*4+0]=e.x;  uB[j4*4+1]=e.y;  uB[j4*4+2]=e.z;  uB[j4*4+3]=e.w;
    }
    const float bias1 = bih[r1] + bhh[r1];
    const float bias2 = bih[r2] + bhh[r2];

    float wfcr[6];
    #pragma unroll
    for (int j = 0; j < 6; j++) wfcr[j] = Wfc[k*6 + j];
    const float bfcl  = bfc[k];
    const float woutl = (lane < 32) ? Wout[k] : 0.f;
    const float boutv = bout[0];

    // fixed-layer RY constants: uniform cos (SGPR) + per-lane parity-signed sin
    float cgv[18], ssin[18];
    #pragma unroll
    for (int g = 0; g < 18; g++){
        int l = g / 6, q = g % 6;
        float a = 0.5f * qw[g];
        float cv = __cosf(a), sv = __sinf(a);
        cgv[g] = rfl(cv);
        unsigned sm = (unsigned)QM.S[l][q];
        ssin[g] = (__builtin_popcount(sm & lane) & 1) ? sv : -sv;
    }
    float wsgn[6];
    #pragma unroll
    for (int j = 0; j < 6; j++) wsgn[j] = (lane & (1u << j)) ? -1.f : 1.f;
    const bool qs[6] = { (lane & 32u) != 0, (lane & 16u) != 0, (lane & 8u) != 0,
                         (lane & 4u) != 0,  (lane & 2u) != 0,  (lane & 1u) != 0 };

    float h = 0.f, c = 0.f;
    const float* xbase = tS + (size_t)b * HC;

    float4 xf[8];
    #pragma unroll
    for (int j4 = 0; j4 < 8; j4++) xf[j4] = ((const float4*)xbase)[j4];

    #pragma clang loop unroll(disable)
    for (int s = 0; s < T_LEN; s++){
        float xt[32];
        #pragma unroll
        for (int j4 = 0; j4 < 8; j4++){
            xt[j4*4+0]=xf[j4].x; xt[j4*4+1]=xf[j4].y; xt[j4*4+2]=xf[j4].z; xt[j4*4+3]=xf[j4].w;
        }
        { // prefetch next step
            int s2 = (s + 1 < T_LEN) ? s + 1 : s;
            const float4* np_ = (const float4*)(xbase + (size_t)s2*(B_SIZE*HC));
            #pragma unroll
            for (int j4 = 0; j4 < 8; j4++) xf[j4] = np_[j4];
        }

        // ---- LSTM gates ----
        float a1a = bias1, a1b = 0.f, a2a = bias2, a2b = 0.f;
        #pragma unroll
        for (int j = 0; j < 32; j += 2){
            a1a += xt[j]*wA[j];     a1b += xt[j+1]*wA[j+1];
            a2a += xt[j]*wB[j];     a2b += xt[j+1]*wB[j+1];
        }
        #pragma unroll
        for (int j = 0; j < 32; j += 2){
            float h0 = rdlane(h, j), h1 = rdlane(h, j+1);
            a1a += h0*uA[j];   a1b += h1*uA[j+1];
            a2a += h0*uB[j];   a2b += h1*uB[j+1];
        }
        float acc1 = a1a + a1b, acc2 = a2a + a2b;

        float sigA = fsigmoid(acc1);                 // low: sig(i), high: sig(f)
        float argB = (lane < 32) ? acc2 : 0.5f*acc2; // low: tanh(g), high: sig(o)
        float tt   = ftanh(argB);
        float actB = (lane < 32) ? tt : (0.5f + 0.5f*tt);
        float fsig = xshuf<32>(sigA, lane);
        float osig = xshuf<32>(actB, lane);
        c = fsig*c + sigA*actB;
        float hn = osig * ftanh(c);

        // ---- logistic + henon ----
        hn = 3.99f * hn * (1.f - hn);
        float x0 = rdlane(hn, 0), y0 = rdlane(hn, 1);
        float xnv = 1.f - 1.4f*x0*x0 + y0;
        float ynv = 0.3f * x0;

        // ---- quantum circuit: product-state init ----
        float ang[6];
        ang[0] = 0.5f*xnv; ang[1] = 0.5f*ynv;
        ang[2] = 0.5f*rdlane(hn, 2); ang[3] = 0.5f*rdlane(hn, 3);
        ang[4] = 0.5f*rdlane(hn, 4); ang[5] = 0.5f*rdlane(hn, 5);
        float ca[6], sa[6];
        #pragma unroll
        for (int j = 0; j < 6; j++){ ca[j] = __cosf(ang[j]); sa[j] = __sinf(ang[j]); }

        float fr[6], fi[6];
        #pragma unroll
        for (int i = 0; i < 6; i++){
            const int i1 = (i+1)%6, i2 = (i+2)%6;
            float cx=ca[i], sx=sa[i], cy=ca[i1], sy=sa[i1], cz=ca[i2], sz=sa[i2];
            float w0r = cy*cx, w0i = sy*sx;       // RY*RX|0>
            float w1r = sy*cx, w1i = -cy*sx;
            float q0r = cz*w0r + sz*w0i, q0i = cz*w0i - sz*w0r;   // * e^{-i az}
            float q1r = cz*w1r - sz*w1i, q1i = cz*w1i + sz*w1r;   // * e^{+i az}
            fr[i] = qs[i] ? q1r : q0r;
            fi[i] = qs[i] ? q1i : q0i;
        }
        float t01r = fr[0]*fr[1] - fi[0]*fi[1], t01i = fr[0]*fi[1] + fi[0]*fr[1];
        float t23r = fr[2]*fr[3] - fi[2]*fi[3], t23i = fr[2]*fi[3] + fi[2]*fr[3];
        float t45r = fr[4]*fr[5] - fi[4]*fi[5], t45i = fr[4]*fi[5] + fi[4]*fr[5];
        float t03r = t01r*t23r - t01i*t23i,     t03i = t01r*t23i + t01i*t23r;
        float ar   = t03r*t45r - t03i*t45i,     ai   = t03r*t45i + t03i*t45r;

        // ---- entangling layers: RY as xor-exchange in relabeled basis ----
        #define GATE(L,Q) { \
            constexpr int MM = QM.M[L][Q]; \
            float br = xshuf<MM>(ar, lane), bi = xshuf<MM>(ai, lane); \
            float cg = cgv[(L)*6+(Q)], ss = ssin[(L)*6+(Q)]; \
            ar = cg*ar + ss*br; ai = cg*ai + ss*bi; }
        GATE(0,0) GATE(0,1) GATE(0,2) GATE(0,3) GATE(0,4) GATE(0,5)
        GATE(1,0) GATE(1,1) GATE(1,2) GATE(1,3) GATE(1,4) GATE(1,5)
        GATE(2,0) GATE(2,1) GATE(2,2) GATE(2,3) GATE(2,4) GATE(2,5)
        #undef GATE

        // ---- expvals: full Walsh-Hadamard butterfly, pick rows of Pi^-3 ----
        float wp = ar*ar + ai*ai;
        wp = wsgn[0]*wp + xshuf< 1>(wp, lane);
        wp = wsgn[1]*wp + xshuf< 2>(wp, lane);
        wp = wsgn[2]*wp + xshuf< 4>(wp, lane);
        wp = wsgn[3]*wp + xshuf< 8>(wp, lane);
        wp = wsgn[4]*wp + xshuf<16>(wp, lane);
        wp = wsgn[5]*wp + xshuf<32>(wp, lane);
        float ev0 = rdlane(wp, QM.R[0]), ev1 = rdlane(wp, QM.R[1]);
        float ev2 = rdlane(wp, QM.R[2]), ev3 = rdlane(wp, QM.R[3]);
        float ev4 = rdlane(wp, QM.R[4]), ev5 = rdlane(wp, QM.R[5]);

        float upd = bfcl + (wfcr[0]*ev0 + wfcr[1]*ev1)
                         + (wfcr[2]*ev2 + wfcr[3]*ev3)
                         + (wfcr[4]*ev4 + wfcr[5]*ev5);

        float hsel = hn;
        hsel = (lane == 0u) ? xnv : hsel;
        hsel = (lane == 1u) ? ynv : hsel;
        h = hsel + upd;
    }

    // ---- output: sigmoid(h . Wout + bout) ----
    float pv = (lane < 32) ? h*woutl : 0.f;
    #pragma unroll
    for (int off = 32; off; off >>= 1) pv += __shfl_xor(pv, off, 64);
    if (lane == 0) out[b] = fsigmoid(pv + boutv);
}

extern "C" void kernel_launch(void* const* d_in, const int* in_sizes, int n_in,
                              void* d_out, int out_size, void* d_ws, size_t ws_size,
                              hipStream_t stream)
{
    (void)in_sizes; (void)n_in; (void)out_size; (void)ws_size;
    const float* x    = (const float*)d_in[0];
    const float* w0   = (const float*)d_in[1];
    const float* b0   = (const float*)d_in[2];
    const float* w1   = (const float*)d_in[3];
    const float* b1   = (const float*)d_in[4];
    const float* w2   = (const float*)d_in[5];
    const float* b2   = (const float*)d_in[6];
    const float* Wih  = (const float*)d_in[7];
    const float* Whh  = (const float*)d_in[8];
    const float* bih  = (const float*)d_in[9];
    const float* bhh  = (const float*)d_in[10];
    const float* qw   = (const float*)d_in[11];
    const float* Wfc  = (const float*)d_in[12];
    const float* bfc  = (const float*)d_in[13];
    const float* Wout = (const float*)d_in[14];
    const float* bout = (const float*)d_in[15];
    float* out = (float*)d_out;

    float* t0 = (float*)d_ws;                              // (B,32,T) 32 MB
    float* t1 = t0 + (size_t)B_SIZE*HC*T_LEN;              // (B,32,T) 32 MB
    float* tS = t0;                                        // (T,B,32) reuses t0

    conv0_kernel<<<2048, 256, 0, stream>>>(x, w0, b0, t0);
    convm_kernel<false><<<2048, 256, 0, stream>>>(t0, w1, b1, t1);
    convm_kernel<true ><<<2048, 256, 0, stream>>>(t1, w2, b2, tS);
    scan_kernel<<<256, 256, 0, stream>>>(tS, Wih, Whh, bih, bhh, qw, Wfc, bfc, Wout, bout, out);
}